// Round 5
// baseline (489.862 us; speedup 1.0000x reference)
//
#include <hip/hip_runtime.h>
#include <hip/hip_bf16.h>
#include <stdint.h>

typedef __attribute__((ext_vector_type(8))) short bf16x8;
typedef __attribute__((ext_vector_type(4))) float f32x4;
typedef unsigned short u16;
typedef unsigned int u32;

#define GLL(gp, lp) __builtin_amdgcn_global_load_lds( \
    (const __attribute__((address_space(1))) void*)(gp), \
    (__attribute__((address_space(3))) void*)(lp), 16, 0, 0)

__device__ __forceinline__ u16 f2bf_rne(float v) {
    u32 u = __float_as_uint(v);
    u32 r = (u + 0x7fffu + ((u >> 16) & 1u)) >> 16;
    return (u16)r;
}

// ---------------- pack kernels ----------------

// x (2048,39,16) f32  ->  xbd [32768][40] bf16, m = b*16+d, col 39 zero-pad
__global__ void pack_x_kernel(const float* __restrict__ x, u16* __restrict__ xbd) {
    int idx = blockIdx.x * 256 + threadIdx.x;
    if (idx >= 32768 * 40) return;
    int m = idx / 40, f = idx - m * 40;
    int b = m >> 4, d = m & 15;
    float v = (f < 39) ? x[(b * 39 + f) * 16 + d] : 0.0f;
    xbd[idx] = f2bf_rne(v);
}

// W0 (200,39,39) f32 -> Wp [224][1792] bf16, k = f*40+g, zero-padded
__global__ void pack_w0_kernel(const float* __restrict__ W, u16* __restrict__ Wp) {
    int idx = blockIdx.x * 256 + threadIdx.x;
    if (idx >= 224 * 1792) return;
    int o = idx / 1792, k = idx - o * 1792;
    int f = k / 40, g = k - f * 40;
    float v = (o < 200 && f < 39 && g < 39) ? W[(o * 39 + f) * 39 + g] : 0.0f;
    Wp[idx] = f2bf_rne(v);
}

// W1/W2 (200,39,200) f32 -> Wp [224][8192] bf16, k = f*208+g, zero-padded
__global__ void pack_w12_kernel(const float* __restrict__ W, u16* __restrict__ Wp) {
    int idx = blockIdx.x * 256 + threadIdx.x;
    if (idx >= 224 * 8192) return;
    int o = idx / 8192, k = idx - o * 8192;
    int f = k / 208, g = k - f * 208;
    float v = (o < 200 && f < 39 && g < 200) ? W[o * 7800 + f * 200 + g] : 0.0f;
    Wp[idx] = f2bf_rne(v);
}

// ---------------- main GEMM kernel ----------------
// C[m,o] = sum_k A[m,k]*Wp[o,k],  A[m, f*GS+g] = xbd[m,f]*h[m,g]
// grid 256 = 128 M-blocks x 2 N-halves. block: 512 thr = 8 waves = 4 mg x 2 kg.
// X,H staged in LDS once (global_load_lds). W: per-wave register double-buffer,
// direct global loads (L2-resident, 3.6 MB). ZERO barriers in the main loop.
template <int LAYER>
__global__ __launch_bounds__(512, 2) void cin_gemm5(
    const u16* __restrict__ Xbd,    // [32768][40] bf16
    const u16* __restrict__ Hin,    // [32768][208] bf16 (LAYER>0)
    const u16* __restrict__ Wp,     // [224][KP] bf16
    const float* __restrict__ bias, // [200] f32
    u16* __restrict__ Hout,         // [32768][208] bf16 (LAYER<2)
    float* __restrict__ out)        // [2048][600] f32
{
    constexpr int KP    = (LAYER == 0) ? 1792 : 8192;
    constexpr int NPAIR = KP / 64;          // 28 / 128 (even!)
    constexpr u32 MAGIC = (LAYER == 0) ? 3277u : 10083u;
    constexpr int SHIFT = (LAYER == 0) ? 17 : 21;
    constexpr int GS    = (LAYER == 0) ? 40 : 208;     // k = f*GS + g
    constexpr int GCL   = (LAYER == 0) ? 32 : 200;     // g0 clamp (8-aligned, in-row)
    constexpr int HROW  = (LAYER == 0) ? 40 : 208;     // h LDS row stride (elements)
    constexpr int HSZ   = (LAYER == 0) ? 0 : 106496;   // 256*208*2
    constexpr int SMEMA = 20480 + HSZ;
    constexpr int SMEM  = (SMEMA > 114688) ? SMEMA : 114688;  // epilogue red[] needs 114688

    __shared__ __align__(16) char smem[SMEM];
    u16* Xl = (u16*)smem;
    u16* Hl = (u16*)(smem + 20480);

    const int bid  = blockIdx.x;
    const int mblk = bid >> 1, nblk = bid & 1;
    const int m0    = mblk * 256;
    const int ncol0 = nblk * 112;
    const int NT    = nblk ? 6 : 7;
    const int tid  = threadIdx.x;
    const int lane = tid & 63, wid = tid >> 6;
    const int mg = wid & 3, kg = wid >> 2;
    const int rowl = lane & 15, grp = lane >> 4;

    // ---- stage X (once) ----
    {
        const char* xsrc = (const char*)(Xbd + (size_t)m0 * 40);
        for (int i = wid; i < 20; i += 8)
            GLL(xsrc + i * 1024 + lane * 16, smem + i * 1024);
    }
    // ---- stage H (once) ----
    if constexpr (LAYER > 0) {
        const char* hsrc = (const char*)(Hin + (size_t)m0 * 208);
        for (int i = wid; i < 104; i += 8)
            GLL(hsrc + i * 1024 + lane * 16, smem + 20480 + i * 1024);
    }

    int xro[4], hro[4];
    #pragma unroll
    for (int s = 0; s < 4; ++s) {
        int r = mg * 64 + s * 16 + rowl;
        xro[s] = r * 40;
        hro[s] = r * HROW;
    }
    const u16* Hb = (LAYER == 0) ? Xl : Hl;

    f32x4 acc[4][7];
    #pragma unroll
    for (int s = 0; s < 4; ++s)
        #pragma unroll
        for (int t = 0; t < 7; ++t) {
            f32x4 z = {0.f, 0.f, 0.f, 0.f};
            acc[s][t] = z;
        }

    // per-wave B base: row = ncol0 + t*16 + rowl, col = kg*32 + grp*8 (+pr*64)
    const u16* WbBase = Wp + (size_t)(ncol0 + rowl) * KP + kg * 32 + grp * 8;

    bf16x8 bA[7], bB[7];

#define LOADB(koff, dst) { \
    _Pragma("unroll") \
    for (int t = 0; t < 7; ++t) \
        dst[t] = *(const bf16x8*)(WbBase + (size_t)t * 16 * KP + (koff)); }

#define COMPUTE(pr, bR) { \
    int k0 = (pr) * 64 + kg * 32 + grp * 8; \
    u32 f = ((u32)k0 * MAGIC) >> SHIFT; \
    f = (f > 39u) ? 39u : f; \
    int g0 = k0 - (int)f * GS; \
    g0 = (g0 > GCL) ? GCL : g0; \
    bf16x8 afrag[4]; \
    _Pragma("unroll") \
    for (int s = 0; s < 4; ++s) { \
        u16 xs = Xl[xro[s] + (int)f]; \
        bf16x8 hv = *(const bf16x8*)&Hb[hro[s] + g0]; \
        float xf = __uint_as_float(((u32)xs) << 16); \
        union { bf16x8 v; u32 w[4]; } hu, au; \
        hu.v = hv; \
        _Pragma("unroll") \
        for (int j = 0; j < 4; ++j) { \
            float lo = __uint_as_float(hu.w[j] << 16); \
            float hi = __uint_as_float(hu.w[j] & 0xffff0000u); \
            float pl = xf * lo, ph2 = xf * hi; \
            u32 pk; \
            asm("v_cvt_pk_bf16_f32 %0, %1, %2" : "=v"(pk) : "v"(pl), "v"(ph2)); \
            au.w[j] = pk; \
        } \
        afrag[s] = au.v; \
    } \
    _Pragma("unroll") \
    for (int t = 0; t < 7; ++t) { \
        _Pragma("unroll") \
        for (int s = 0; s < 4; ++s) \
            acc[s][t] = __builtin_amdgcn_mfma_f32_16x16x32_bf16(afrag[s], bR[t], acc[s][t], 0, 0, 0); \
    } }

    LOADB(0, bA);
    __syncthreads();   // X/H staged (drains vmcnt); bA also complete

    for (int pr = 0; pr < NPAIR; pr += 2) {
        LOADB((pr + 1) * 64, bB);
        COMPUTE(pr, bA);
        if (pr + 2 < NPAIR) LOADB((pr + 2) * 64, bA);
        COMPUTE(pr + 1, bB);
    }
#undef LOADB
#undef COMPUTE

    // ---- merge kg pair partials via LDS (reuses smem; X/H dead) ----
    __syncthreads();
    float* red = (float*)smem;
    const int rbase = mg * 7168 + lane * 4;
    if (kg == 1) {
        #pragma unroll
        for (int s = 0; s < 4; ++s)
            #pragma unroll
            for (int t = 0; t < 7; ++t)
                if (t < NT)
                    *(f32x4*)&red[rbase + (s * 7 + t) * 256] = acc[s][t];
    }
    __syncthreads();

    if (kg == 0) {
        float bias_t[7];
        #pragma unroll
        for (int t = 0; t < 7; ++t) {
            int oc = ncol0 + t * 16 + rowl;
            bias_t[t] = (t < NT && oc < 200) ? bias[oc] : 0.0f;
        }
        #pragma unroll
        for (int s = 0; s < 4; ++s) {
            int mrow0 = m0 + mg * 64 + s * 16;   // 16 rows = one batch index
            int bidx = mrow0 >> 4;
            #pragma unroll
            for (int t = 0; t < 7; ++t) {
                if (t < NT) {
                    int oc = ncol0 + t * 16 + rowl;
                    f32x4 o = *(const f32x4*)&red[rbase + (s * 7 + t) * 256];
                    f32x4 v = acc[s][t];
                    float h0 = fmaxf(v[0] + o[0] + bias_t[t], 0.0f);
                    float h1 = fmaxf(v[1] + o[1] + bias_t[t], 0.0f);
                    float h2 = fmaxf(v[2] + o[2] + bias_t[t], 0.0f);
                    float h3 = fmaxf(v[3] + o[3] + bias_t[t], 0.0f);
                    if constexpr (LAYER < 2) {
                        size_t rb = (size_t)(mrow0 + grp * 4) * 208 + oc;
                        Hout[rb]           = f2bf_rne(h0);
                        Hout[rb + 208]     = f2bf_rne(h1);
                        Hout[rb + 2*208]   = f2bf_rne(h2);
                        Hout[rb + 3*208]   = f2bf_rne(h3);
                    }
                    float ssum = (h0 + h1) + (h2 + h3);
                    ssum += __shfl_xor(ssum, 16);
                    ssum += __shfl_xor(ssum, 32);
                    if (grp == 0 && oc < 200)
                        out[(size_t)bidx * 600 + LAYER * 200 + oc] = ssum;
                }
            }
        }
    }
}

// ---------------- launch ----------------
extern "C" void kernel_launch(void* const* d_in, const int* in_sizes, int n_in,
                              void* d_out, int out_size, void* d_ws, size_t ws_size,
                              hipStream_t stream) {
    const float* x  = (const float*)d_in[0];
    const float* W0 = (const float*)d_in[1];
    const float* b0 = (const float*)d_in[2];
    const float* W1 = (const float*)d_in[3];
    const float* b1 = (const float*)d_in[4];
    const float* W2 = (const float*)d_in[5];
    const float* b2 = (const float*)d_in[6];
    float* out = (float*)d_out;

    char* ws = (char*)d_ws;
    // workspace layout (16B aligned)
    u16* xbd = (u16*)(ws);                     // 32768*40*2  = 2,621,440 (+1024 slack)
    u16* wp0 = (u16*)(ws + 2622464);           // 224*1792*2  =   802,816
    u16* wp1 = (u16*)(ws + 3425280);           // 224*8192*2  = 3,670,016
    u16* wp2 = (u16*)(ws + 7095296);           // 3,670,016
    u16* h1  = (u16*)(ws + 10765312);          // 32768*208*2 = 13,631,488 (+1024 slack)
    u16* h2  = (u16*)(ws + 24397824);          // 13,631,488 (+1024 slack)

    pack_x_kernel<<<5120, 256, 0, stream>>>(x, xbd);
    pack_w0_kernel<<<1568, 256, 0, stream>>>(W0, wp0);
    pack_w12_kernel<<<7168, 256, 0, stream>>>(W1, wp1);
    pack_w12_kernel<<<7168, 256, 0, stream>>>(W2, wp2);

    cin_gemm5<0><<<256, 512, 0, stream>>>(xbd, xbd, wp0, b0, h1, out);
    cin_gemm5<1><<<256, 512, 0, stream>>>(xbd, h1, wp1, b1, h2, out);
    cin_gemm5<2><<<256, 512, 0, stream>>>(xbd, h2, wp2, b2, (u16*)nullptr, out);
}

// Round 8
// 309.139 us; speedup vs baseline: 1.5846x; 1.5846x over previous
//
#include <hip/hip_runtime.h>
#include <hip/hip_bf16.h>
#include <stdint.h>

typedef __attribute__((ext_vector_type(8))) short bf16x8;
typedef __attribute__((ext_vector_type(4))) float f32x4;
typedef __attribute__((ext_vector_type(16))) float f32x16;
typedef unsigned short u16;
typedef unsigned int u32;

#define GLL(gp, lp) __builtin_amdgcn_global_load_lds( \
    (const __attribute__((address_space(1))) void*)(gp), \
    (__attribute__((address_space(3))) void*)(lp), 16, 0, 0)

__device__ __forceinline__ u16 f2bf_rne(float v) {
    u32 u = __float_as_uint(v);
    u32 r = (u + 0x7fffu + ((u >> 16) & 1u)) >> 16;
    return (u16)r;
}

// ---------------- pack kernels ----------------

// x (2048,39,16) f32  ->  xbd [32768][40] bf16, m = b*16+d, col 39 zero-pad
__global__ void pack_x_kernel(const float* __restrict__ x, u16* __restrict__ xbd) {
    int idx = blockIdx.x * 256 + threadIdx.x;
    if (idx >= 32768 * 40) return;
    int m = idx / 40, f = idx - m * 40;
    int b = m >> 4, d = m & 15;
    float v = (f < 39) ? x[(b * 39 + f) * 16 + d] : 0.0f;
    xbd[idx] = f2bf_rne(v);
}

// W -> MFMA-fragment-packed stream Wpk[((ks*7 + nt)*64 + lane)*8 + j]
// o = nt*32 + (lane&31), k = ks*16 + (lane>>5)*8 + j, k = f*GS + g
template <int LAYER>
__global__ void pack_wfrag_kernel(const float* __restrict__ W, u16* __restrict__ Wpk) {
    constexpr int TOT = (LAYER == 0) ? 401408 : 1835008;   // ks*7*512
    int idx = blockIdx.x * 256 + threadIdx.x;
    if (idx >= TOT) return;
    int j = idx & 7;
    int lane = (idx >> 3) & 63;
    int rest = idx >> 9;
    int nt = rest % 7, ks = rest / 7;
    int o = nt * 32 + (lane & 31);
    int k = ks * 16 + ((lane >> 5) << 3) + j;
    float v = 0.0f;
    if constexpr (LAYER == 0) {
        int f = k / 40, g = k - f * 40;
        if (o < 200 && f < 39 && g < 39) v = W[(o * 39 + f) * 39 + g];
    } else {
        int f = k / 208, g = k - f * 208;
        if (o < 200 && f < 39 && g < 200) v = W[o * 7800 + f * 200 + g];
    }
    Wpk[idx] = f2bf_rne(v);
}

// ---------------- main GEMM kernel ----------------
// C[m,o] = sum_k A[m,k]*W[o,k],  A[m, f*GS+g] = xbd[m,f]*h[m,g]
// grid 256 blocks (1/CU): block = 128 rows x 224 cols. 8 waves = 2mg x 2ng x 2kg.
// 32x32x16 MFMA. Wave: 2 M-subtiles x {4|3} N-tiles, acc f32x16[2][4].
// B: fragment-packed W, per-wave contiguous 1KB register loads (L2), dbuf 2 ksteps.
// NO barriers in main loop. h,x in LDS. All reads deterministic (g0 clamp keeps
// LDS reads in staged regions; Hout pad cols 200..207 written to 0).
template <int LAYER>
__global__ __launch_bounds__(512, 2) void cin_gemm6(
    const u16* __restrict__ Xbd,    // [32768][40] bf16
    const u16* __restrict__ Hin,    // [32768][208] bf16 (LAYER>0)
    const u16* __restrict__ Bpk,    // fragment-packed W
    const float* __restrict__ bias, // [200] f32
    u16* __restrict__ Hout,         // [32768][208] bf16 (LAYER<2)
    float* __restrict__ out)        // [2048][600] f32
{
    constexpr int KP    = (LAYER == 0) ? 1792 : 8192;
    constexpr int NITER = KP / 64;                     // 28 / 128 (even)
    constexpr u32 MAGIC = (LAYER == 0) ? 3277u : 10083u;
    constexpr int SHIFT = (LAYER == 0) ? 17 : 21;
    constexpr int GS    = (LAYER == 0) ? 40 : 208;
    constexpr int GCL   = (LAYER == 0) ? 32 : 200;     // g0 clamp (8-aligned, in staged region)
    constexpr int HROW  = (LAYER == 0) ? 40 : 216;     // LDS row stride (elems)

    __shared__ __align__(16) char smem[114688];        // X 10240 | H 55296 ; reused as red
    u16* Xl = (u16*)smem;
    u16* Hl = (u16*)(smem + 10240);

    const int bid  = blockIdx.x;
    const int m0   = bid * 128;
    const int tid  = threadIdx.x;
    const int lane = tid & 63, wid = tid >> 6;
    const int mg = wid & 1, kg = (wid >> 1) & 1, ng = wid >> 2;
    const int l31 = lane & 31, grp8 = lane >> 5;
    const int nt0 = ng * 4;
    const int NTW = ng ? 3 : 4;

    // ---- stage X via global_load_lds (10 KB linear) ----
    {
        const char* xsrc = (const char*)(Xbd + (size_t)m0 * 40);
        for (int i = wid; i < 10; i += 8)
            GLL(xsrc + i * 1024 + lane * 16, smem + i * 1024);
    }
    // ---- stage H: global -> regs -> padded LDS rows (stride 216) ----
    if constexpr (LAYER > 0) {
        const u16* hsrc = Hin + (size_t)m0 * 208;
        #pragma unroll
        for (int j = 0; j < 7; ++j) {
            int u = tid + j * 512;
            if (u < 3328) {
                int r = u / 26, q = u - r * 26;
                int4 v = *(const int4*)(hsrc + r * 208 + q * 8);
                *(int4*)(Hl + r * 216 + q * 8) = v;
            }
        }
    }

    int xrow40[2], hrow[2];
    #pragma unroll
    for (int sub = 0; sub < 2; ++sub) {
        int r = mg * 64 + sub * 32 + l31;
        xrow40[sub] = r * 40;
        hrow[sub]   = r * HROW;
    }
    const u16* Hb = (LAYER == 0) ? Xl : Hl;

    f32x16 acc[2][4];
    #pragma unroll
    for (int s = 0; s < 2; ++s)
        #pragma unroll
        for (int t = 0; t < 4; ++t)
            acc[s][t] = (f32x16){0,0,0,0,0,0,0,0,0,0,0,0,0,0,0,0};

    bf16x8 bA[2][4], bB[2][4];

#define LOADB2(it_, dst) { \
    _Pragma("unroll") \
    for (int s_ = 0; s_ < 2; ++s_) { \
        int ks_ = 4 * (it_) + 2 * kg + s_; \
        _Pragma("unroll") \
        for (int t_ = 0; t_ < 4; ++t_) \
            if (t_ < NTW) \
                dst[s_][t_] = *(const bf16x8*)(Bpk + (size_t)ks_ * 3584 + (nt0 + t_) * 512 + lane * 8); \
    } }

#define COMPUTE2(it_, src) { \
    _Pragma("unroll") \
    for (int s_ = 0; s_ < 2; ++s_) { \
        int ks_ = 4 * (it_) + 2 * kg + s_; \
        int k0_ = ks_ * 16 + grp8 * 8; \
        u32 f_ = ((u32)k0_ * MAGIC) >> SHIFT; \
        f_ = (f_ > 39u) ? 39u : f_; \
        int g0_ = k0_ - (int)f_ * GS; \
        g0_ = (g0_ > GCL) ? GCL : g0_; \
        _Pragma("unroll") \
        for (int sub_ = 0; sub_ < 2; ++sub_) { \
            u16 xs_ = Xl[xrow40[sub_] + (int)f_]; \
            bf16x8 hv_ = *(const bf16x8*)&Hb[hrow[sub_] + g0_]; \
            float xf_ = __uint_as_float(((u32)xs_) << 16); \
            union { bf16x8 v; u32 w[4]; } hu_, au_; \
            hu_.v = hv_; \
            _Pragma("unroll") \
            for (int j_ = 0; j_ < 4; ++j_) { \
                float lo_ = __uint_as_float(hu_.w[j_] << 16); \
                float hi_ = __uint_as_float(hu_.w[j_] & 0xffff0000u); \
                float pl_ = xf_ * lo_, ph_ = xf_ * hi_; \
                u32 pk_; \
                asm("v_cvt_pk_bf16_f32 %0, %1, %2" : "=v"(pk_) : "v"(pl_), "v"(ph_)); \
                au_.w[j_] = pk_; \
            } \
            bf16x8 af_ = au_.v; \
            _Pragma("unroll") \
            for (int t_ = 0; t_ < 4; ++t_) \
                if (t_ < NTW) \
                    acc[sub_][t_] = __builtin_amdgcn_mfma_f32_32x32x16_bf16(af_, src[s_][t_], acc[sub_][t_], 0, 0, 0); \
        } \
    } }

    LOADB2(0, bA);
    __syncthreads();   // X/H staged; free-run from here

    for (int it = 0; it < NITER; it += 2) {
        LOADB2(it + 1, bB);
        COMPUTE2(it, bA);
        if (it + 2 < NITER) LOADB2(it + 2, bA);
        COMPUTE2(it + 1, bB);
    }
#undef LOADB2
#undef COMPUTE2

    // ---- kg merge via LDS red (X/H dead) ----
    __syncthreads();
    float* red = (float*)smem;   // tile T: [T*1024 + lane*16 + r], T = (mg*2+sub)*7 + nt
    if (kg == 1) {
        #pragma unroll
        for (int sub = 0; sub < 2; ++sub)
            #pragma unroll
            for (int t = 0; t < 4; ++t)
                if (t < NTW) {
                    int T = (mg * 2 + sub) * 7 + nt0 + t;
                    float* p = red + T * 1024 + lane * 16;
                    f32x16 a = acc[sub][t];
                    *(f32x4*)(p + 0)  = (f32x4){a[0], a[1], a[2], a[3]};
                    *(f32x4*)(p + 4)  = (f32x4){a[4], a[5], a[6], a[7]};
                    *(f32x4*)(p + 8)  = (f32x4){a[8], a[9], a[10], a[11]};
                    *(f32x4*)(p + 12) = (f32x4){a[12], a[13], a[14], a[15]};
                }
    }
    __syncthreads();

    if (kg == 0) {
        #pragma unroll
        for (int sub = 0; sub < 2; ++sub) {
            int rowbase = m0 + mg * 64 + sub * 32;
            int bA0 = rowbase >> 4;
            #pragma unroll
            for (int t = 0; t < 4; ++t) {
                if (t < NTW) {
                    int T = (mg * 2 + sub) * 7 + nt0 + t;
                    const float* p = red + T * 1024 + lane * 16;
                    f32x4 o0 = *(const f32x4*)(p + 0);
                    f32x4 o1 = *(const f32x4*)(p + 4);
                    f32x4 o2 = *(const f32x4*)(p + 8);
                    f32x4 o3 = *(const f32x4*)(p + 12);
                    int oc = nt0 * 32 + t * 32 + l31;
                    float bs = (oc < 200) ? bias[oc] : 0.0f;
                    f32x16 a = acc[sub][t];
                    float hv[16];
                    #pragma unroll
                    for (int r = 0; r < 4; ++r) {
                        hv[r]      = fmaxf(a[r]      + o0[r] + bs, 0.0f);
                        hv[r + 4]  = fmaxf(a[r + 4]  + o1[r] + bs, 0.0f);
                        hv[r + 8]  = fmaxf(a[r + 8]  + o2[r] + bs, 0.0f);
                        hv[r + 12] = fmaxf(a[r + 12] + o3[r] + bs, 0.0f);
                    }
                    if constexpr (LAYER < 2) {
                        // oc in [200,208): acc==0 (B-pad zero) -> writes 0 pad cols deterministically
                        if (oc < 208) {
                            #pragma unroll
                            for (int r = 0; r < 16; ++r) {
                                int rl = (r & 3) + 8 * (r >> 2) + 4 * grp8;
                                Hout[(size_t)(rowbase + rl) * 208 + oc] = f2bf_rne(hv[r]);
                            }
                        }
                    }
                    float sA = ((hv[0] + hv[1]) + (hv[2] + hv[3])) + ((hv[4] + hv[5]) + (hv[6] + hv[7]));
                    float sB = ((hv[8] + hv[9]) + (hv[10] + hv[11])) + ((hv[12] + hv[13]) + (hv[14] + hv[15]));
                    sA += __shfl_xor(sA, 32);
                    sB += __shfl_xor(sB, 32);
                    if (lane < 32 && oc < 200) {
                        out[(size_t)bA0 * 600 + LAYER * 200 + oc] = sA;
                        out[(size_t)(bA0 + 1) * 600 + LAYER * 200 + oc] = sB;
                    }
                }
            }
        }
    }
}

// ---------------- launch ----------------
extern "C" void kernel_launch(void* const* d_in, const int* in_sizes, int n_in,
                              void* d_out, int out_size, void* d_ws, size_t ws_size,
                              hipStream_t stream) {
    const float* x  = (const float*)d_in[0];
    const float* W0 = (const float*)d_in[1];
    const float* b0 = (const float*)d_in[2];
    const float* W1 = (const float*)d_in[3];
    const float* b1 = (const float*)d_in[4];
    const float* W2 = (const float*)d_in[5];
    const float* b2 = (const float*)d_in[6];
    float* out = (float*)d_out;

    char* ws = (char*)d_ws;
    // workspace layout (16B aligned)
    u16* xbd  = (u16*)(ws);                    // 32768*40*2 = 2,621,440 (+1024 slack)
    u16* wpk0 = (u16*)(ws + 2622464);          // 401,408*2  =   802,816
    u16* wpk1 = (u16*)(ws + 3425280);          // 1,835,008*2 = 3,670,016
    u16* wpk2 = (u16*)(ws + 7095296);          // 3,670,016
    u16* h1   = (u16*)(ws + 10765312);         // 32768*208*2 = 13,631,488 (+1024 slack)
    u16* h2   = (u16*)(ws + 24397824);         // 13,631,488

    pack_x_kernel<<<5120, 256, 0, stream>>>(x, xbd);
    pack_wfrag_kernel<0><<<1568, 256, 0, stream>>>(W0, wpk0);
    pack_wfrag_kernel<1><<<7168, 256, 0, stream>>>(W1, wpk1);
    pack_wfrag_kernel<2><<<7168, 256, 0, stream>>>(W2, wpk2);

    cin_gemm6<0><<<256, 512, 0, stream>>>(xbd, xbd, wpk0, b0, h1, out);
    cin_gemm6<1><<<256, 512, 0, stream>>>(xbd, h1, wpk1, b1, h2, out);
    cin_gemm6<2><<<256, 512, 0, stream>>>(xbd, h2, wpk2, b2, (u16*)nullptr, out);
}